// Round 1
// baseline (1149.119 us; speedup 1.0000x reference)
//
#include <hip/hip_runtime.h>

// ---------- types / helpers ----------
typedef __attribute__((ext_vector_type(8))) short bf16x8;   // MFMA A/B frag (4 VGPRs)
typedef __attribute__((ext_vector_type(4))) float f32x4;    // MFMA C/D frag
typedef __attribute__((ext_vector_type(4))) unsigned int u32x4;     // 16B copy
typedef __attribute__((ext_vector_type(4))) unsigned short us4_t;   // 8B bf16 store

__device__ __forceinline__ unsigned short f2bf(float f) {   // RNE fp32->bf16
  unsigned u = __builtin_bit_cast(unsigned, f);
  u += 0x7fffu + ((u >> 16) & 1u);
  return (unsigned short)(u >> 16);
}
__device__ __forceinline__ float bf2f(unsigned short h) {
  unsigned u = ((unsigned)h) << 16;
  return __builtin_bit_cast(float, u);
}

// ---------- K0: rank-factored neural position bias -> bq/bk [H][256][32] bf16 ----------
// grid (8 h, 8 n-groups), 256 threads: thread = (n_local 0..31, rgroup 0..7), 4 r each.
__global__ __launch_bounds__(256) void bias_kernel(
    const float* __restrict__ mlp1_w, const float* __restrict__ mlp1_b,
    const float* __restrict__ mlp2_w, const float* __restrict__ bias_scale,
    unsigned short* __restrict__ bq_ws, unsigned short* __restrict__ bk_ws) {
  const int h = blockIdx.x;
  const int n = blockIdx.y * 32 + (threadIdx.x >> 3);
  const int rbase = (threadIdx.x & 7) * 4;
  const float inv_denom = 0.36067376022224085f;  // 1/log(16) ; log1p(15)=log(16)>1
  const float c0 = log1pf((float)(n >> 4)) * inv_denom;   // y coord
  const float c1 = log1pf((float)(n & 15)) * inv_denom;   // x coord
  float hf[128];
  for (int j = 0; j < 128; j++) {
    float t = fmaf(c0, mlp1_w[j], fmaf(c1, mlp1_w[128 + j], mlp1_b[j]));
    hf[j] = 0.5f * t * (1.0f + erff(t * 0.70710678118654752f));  // exact gelu
  }
  const float bs = bias_scale[0];
  for (int i = 0; i < 4; i++) {
    int r = rbase + i;
    const float* wcol = mlp2_w + h * 64 + r;   // bqk col = h*64 + s*32 + r
    float sq = 0.f, sk = 0.f;
    for (int j = 0; j < 128; j++) {
      sq = fmaf(hf[j], wcol[j * 512], sq);
      sk = fmaf(hf[j], wcol[j * 512 + 32], sk);
    }
    bq_ws[(h * 256 + n) * 32 + r] = f2bf(bs / (1.f + expf(-sq)));
    bk_ws[(h * 256 + n) * 32 + r] = f2bf(1.f / (1.f + expf(-sk)));
  }
}

// ---------- K1: qkv = x @ qkv_w + qkv_b ; scatter to q(scaled)/k [B,H,N,32], v^T [B,H,32,N] bf16
// 128x128 tile, BK=64, 256 threads (4 waves, each 64x64 = 4x4 mfma tiles).
__global__ __launch_bounds__(256) void qkv_kernel(
    const float* __restrict__ x, const float* __restrict__ w, const float* __restrict__ wb,
    const float* __restrict__ logit_scale,
    unsigned short* __restrict__ q_ws, unsigned short* __restrict__ k_ws,
    unsigned short* __restrict__ v_ws) {
  __shared__ unsigned short As[128 * 72];   // [row][k], stride 72 (pad 8: 2-way banks, 16B aligned)
  __shared__ unsigned short Bs[128 * 72];   // [n][k] (transposed at staging)
  const int tid = threadIdx.x;
  const int n0 = blockIdx.x * 128;          // output col base (x-fastest: shares x tile via LLC)
  const int r0 = blockIdx.y * 128;          // row base
  const int lane = tid & 63, wv = tid >> 6;
  const int quad = lane >> 4, l15 = lane & 15;
  const int wm = (wv & 1) * 64, wn = (wv >> 1) * 64;

  f32x4 acc[4][4];
  for (int i = 0; i < 4; i++)
    for (int j = 0; j < 4; j++) acc[i][j] = (f32x4){0.f, 0.f, 0.f, 0.f};

  for (int kk = 0; kk < 256; kk += 64) {
    __syncthreads();
    // A: 128x64 fp32 -> bf16 (2048 float4, 8/thread, fully coalesced)
    #pragma unroll
    for (int i = 0; i < 8; i++) {
      int g = tid + 256 * i;
      int row = g >> 4, c4 = (g & 15) * 4;
      float4 v = *(const float4*)(x + (size_t)(r0 + row) * 256 + kk + c4);
      unsigned long long p =
          (unsigned long long)f2bf(v.x) | ((unsigned long long)f2bf(v.y) << 16) |
          ((unsigned long long)f2bf(v.z) << 32) | ((unsigned long long)f2bf(v.w) << 48);
      *(unsigned long long*)(&As[row * 72 + c4]) = p;
    }
    // B: w[kk+k][n0+n] -> Bs[n][k] (transpose; coalesced global, scattered 2B LDS writes)
    #pragma unroll
    for (int i = 0; i < 8; i++) {
      int g = tid + 256 * i;
      int k = g >> 5, n4 = (g & 31) * 4;
      float4 v = *(const float4*)(w + (size_t)(kk + k) * 768 + n0 + n4);
      Bs[(n4 + 0) * 72 + k] = f2bf(v.x);
      Bs[(n4 + 1) * 72 + k] = f2bf(v.y);
      Bs[(n4 + 2) * 72 + k] = f2bf(v.z);
      Bs[(n4 + 3) * 72 + k] = f2bf(v.w);
    }
    __syncthreads();
    bf16x8 a[4][2], b[4][2];
    #pragma unroll
    for (int rt = 0; rt < 4; rt++) {
      a[rt][0] = *(const bf16x8*)(&As[(wm + rt * 16 + l15) * 72 + quad * 8]);
      a[rt][1] = *(const bf16x8*)(&As[(wm + rt * 16 + l15) * 72 + 32 + quad * 8]);
    }
    #pragma unroll
    for (int ct = 0; ct < 4; ct++) {
      b[ct][0] = *(const bf16x8*)(&Bs[(wn + ct * 16 + l15) * 72 + quad * 8]);
      b[ct][1] = *(const bf16x8*)(&Bs[(wn + ct * 16 + l15) * 72 + 32 + quad * 8]);
    }
    #pragma unroll
    for (int rt = 0; rt < 4; rt++)
      #pragma unroll
      for (int ct = 0; ct < 4; ct++) {
        acc[rt][ct] = __builtin_amdgcn_mfma_f32_16x16x32_bf16(a[rt][0], b[ct][0], acc[rt][ct], 0, 0, 0);
        acc[rt][ct] = __builtin_amdgcn_mfma_f32_16x16x32_bf16(a[rt][1], b[ct][1], acc[rt][ct], 0, 0, 0);
      }
  }
  // epilogue: C/D layout col=lane&15, row=quad*4+reg (verified m89/m91)
  #pragma unroll
  for (int rt = 0; rt < 4; rt++) {
    const int rowb = r0 + wm + rt * 16 + quad * 4;
    const int bb = rowb >> 8, n = rowb & 255;   // batch / token (4-row group never crosses batch)
    #pragma unroll
    for (int ct = 0; ct < 4; ct++) {
      const int gc = n0 + wn + ct * 16 + l15;   // 0..767
      const int s = gc >> 8, rem = gc & 255, h = rem >> 5, d = rem & 31;
      const float bc = wb[gc];
      if (s == 2) {  // v: transposed [B,H,32,N]; 4 consecutive n per lane -> 8B store
        us4_t pk;
        #pragma unroll
        for (int r = 0; r < 4; r++) pk[r] = f2bf(acc[rt][ct][r] + bc);
        *(us4_t*)(v_ws + ((size_t)(bb * 8 + h) * 32 + d) * 256 + n) = pk;
      } else {
        const float sc = (s == 0) ? logit_scale[h] : 1.0f;  // ref: q = (xW+b)*logit_scale
        unsigned short* dst = (s == 0) ? q_ws : k_ws;
        #pragma unroll
        for (int r = 0; r < 4; r++)
          dst[((size_t)(bb * 8 + h) * 256 + (n + r)) * 32 + d] = f2bf((acc[rt][ct][r] + bc) * sc);
      }
    }
  }
}

// ---------- K2: attention per (b,h). S = [q|bq]@[k|bk]^T (K=64), reg softmax, P->LDS, O=P@V^T
// 4 waves; wave owns 64 query rows -> softmax is wave-local shuffles, no barriers in main loop.
__global__ __launch_bounds__(256) void attn_kernel(
    const unsigned short* __restrict__ q_ws, const unsigned short* __restrict__ k_ws,
    const unsigned short* __restrict__ v_ws, const unsigned short* __restrict__ bq_ws,
    const unsigned short* __restrict__ bk_ws, const float* __restrict__ val_res_scale,
    unsigned short* __restrict__ attn_ws) {
  __shared__ unsigned short kext[256 * 72];    // [key n][feat 0..63 = k|bk], stride 72
  __shared__ unsigned short vT[32 * 264];      // [d][key], stride 264 (2-way banks, 16B aligned)
  __shared__ unsigned short Pb[4][16 * 264];   // per-wave P tile [16 rows][256+pad]
  __shared__ float redbuf[256];
  __shared__ float vmean_s[32];                // val_res_scale[h] * mean_n v[n][d]

  const int tid = threadIdx.x;
  const int bh = blockIdx.x, b = bh >> 3, h = bh & 7;
  const size_t base = (size_t)bh * (256 * 32);

  #pragma unroll
  for (int i = 0; i < 4; i++) {   // k | bk rows (16B chunks, coalesced)
    int c = tid + 256 * i;
    int n = c >> 2, j = (c & 3) * 8;
    *(u32x4*)(&kext[n * 72 + j]) = *(const u32x4*)(k_ws + base + n * 32 + j);
    *(u32x4*)(&kext[n * 72 + 32 + j]) = *(const u32x4*)(bk_ws + (size_t)h * 8192 + n * 32 + j);
  }
  #pragma unroll
  for (int i = 0; i < 4; i++) {   // v^T rows
    int c = tid + 256 * i;
    int d = c >> 5, s8 = (c & 31) * 8;
    *(u32x4*)(&vT[d * 264 + s8]) = *(const u32x4*)(v_ws + base + d * 256 + s8);
  }
  __syncthreads();
  {  // v_mean (2-stage reduce)
    int d = tid & 31, seg = tid >> 5;
    float s = 0.f;
    for (int i = 0; i < 32; i++) s += bf2f(vT[d * 264 + seg * 32 + i]);
    redbuf[seg * 32 + d] = s;
  }
  __syncthreads();
  if (tid < 32) {
    float s = 0.f;
    for (int seg = 0; seg < 8; seg++) s += redbuf[seg * 32 + tid];
    vmean_s[tid] = val_res_scale[h] * s * (1.0f / 256.0f);
  }
  __syncthreads();

  const int lane = tid & 63, wv = tid >> 6, quad = lane >> 4, l15 = lane & 15;
  unsigned short* P = Pb[wv];

  for (int rt = 0; rt < 4; rt++) {
    const int m = wv * 64 + rt * 16 + l15;      // query row; A-frag: m=lane&15, k=quad*8+j
    bf16x8 aq = *(const bf16x8*)(q_ws + base + (size_t)m * 32 + quad * 8);
    bf16x8 abq = *(const bf16x8*)(bq_ws + (size_t)h * 8192 + (size_t)m * 32 + quad * 8);
    f32x4 sacc[16];
    #pragma unroll
    for (int ct = 0; ct < 16; ct++) {           // B-frag: key n=lane&15, k=quad*8+j
      bf16x8 b0 = *(const bf16x8*)(&kext[(ct * 16 + l15) * 72 + quad * 8]);
      bf16x8 b1 = *(const bf16x8*)(&kext[(ct * 16 + l15) * 72 + 32 + quad * 8]);
      f32x4 c = {0.f, 0.f, 0.f, 0.f};
      c = __builtin_amdgcn_mfma_f32_16x16x32_bf16(aq, b0, c, 0, 0, 0);
      c = __builtin_amdgcn_mfma_f32_16x16x32_bf16(abq, b1, c, 0, 0, 0);  // + rank-bias part
      sacc[ct] = c;
    }
    // softmax: lane holds rows quad*4+r at col ct*16+l15 -> max/sum over 16 ct regs + 16-lane shfl
    float rsum[4];
    #pragma unroll
    for (int r = 0; r < 4; r++) {
      float mx = sacc[0][r];
      #pragma unroll
      for (int ct = 1; ct < 16; ct++) mx = fmaxf(mx, sacc[ct][r]);
      #pragma unroll
      for (int off = 1; off < 16; off <<= 1) mx = fmaxf(mx, __shfl_xor(mx, off, 16));
      float s = 0.f;
      #pragma unroll
      for (int ct = 0; ct < 16; ct++) {
        float e = __expf(sacc[ct][r] - mx);
        sacc[ct][r] = e;
        s += e;
      }
      #pragma unroll
      for (int off = 1; off < 16; off <<= 1) s += __shfl_xor(s, off, 16);
      rsum[r] = s;
    }
    // P (unnormalized exp) -> per-wave LDS, C-layout -> A-layout round trip
    #pragma unroll
    for (int ct = 0; ct < 16; ct++)
      #pragma unroll
      for (int r = 0; r < 4; r++)
        P[(quad * 4 + r) * 264 + ct * 16 + l15] = f2bf(sacc[ct][r]);
    __threadfence_block();
    f32x4 o0 = {0.f, 0.f, 0.f, 0.f}, o1 = {0.f, 0.f, 0.f, 0.f};
    #pragma unroll
    for (int s = 0; s < 8; s++) {               // K=256 keys in 8 steps
      bf16x8 ap = *(const bf16x8*)(&P[l15 * 264 + s * 32 + quad * 8]);
      bf16x8 bv0 = *(const bf16x8*)(&vT[l15 * 264 + s * 32 + quad * 8]);          // d = l15
      bf16x8 bv1 = *(const bf16x8*)(&vT[(16 + l15) * 264 + s * 32 + quad * 8]);   // d = 16+l15
      o0 = __builtin_amdgcn_mfma_f32_16x16x32_bf16(ap, bv0, o0, 0, 0, 0);
      o1 = __builtin_amdgcn_mfma_f32_16x16x32_bf16(ap, bv1, o1, 0, 0, 0);
    }
    const int nrow = wv * 64 + rt * 16 + quad * 4;
    const size_t obase = ((size_t)b * 256 + nrow) * 256 + h * 32;
    #pragma unroll
    for (int r = 0; r < 4; r++) {
      float inv = 1.0f / rsum[r];               // C-layout rows == rsum rows
      attn_ws[obase + (size_t)r * 256 + l15] = f2bf(o0[r] * inv + vmean_s[l15]);
      attn_ws[obase + (size_t)r * 256 + 16 + l15] = f2bf(o1[r] * inv + vmean_s[16 + l15]);
    }
    __threadfence_block();  // P reads drained before next rt overwrites
  }
}

// ---------- K3: out = attn @ proj_w + proj_b (fp32 out) ----------
__global__ __launch_bounds__(256) void proj_kernel(
    const unsigned short* __restrict__ A, const float* __restrict__ w,
    const float* __restrict__ wb, float* __restrict__ out) {
  __shared__ unsigned short As[128 * 72];
  __shared__ unsigned short Bs[128 * 72];
  const int tid = threadIdx.x;
  const int n0 = blockIdx.x * 128, r0 = blockIdx.y * 128;
  const int lane = tid & 63, wv = tid >> 6;
  const int quad = lane >> 4, l15 = lane & 15;
  const int wm = (wv & 1) * 64, wn = (wv >> 1) * 64;

  f32x4 acc[4][4];
  for (int i = 0; i < 4; i++)
    for (int j = 0; j < 4; j++) acc[i][j] = (f32x4){0.f, 0.f, 0.f, 0.f};

  for (int kk = 0; kk < 256; kk += 64) {
    __syncthreads();
    #pragma unroll
    for (int i = 0; i < 4; i++) {   // A is already bf16: straight 16B copies
      int g = tid + 256 * i;
      int row = g >> 3, c8 = (g & 7) * 8;
      *(u32x4*)(&As[row * 72 + c8]) = *(const u32x4*)(A + (size_t)(r0 + row) * 256 + kk + c8);
    }
    #pragma unroll
    for (int i = 0; i < 8; i++) {   // B transpose fp32->bf16
      int g = tid + 256 * i;
      int k = g >> 5, n4 = (g & 31) * 4;
      float4 v = *(const float4*)(w + (size_t)(kk + k) * 256 + n0 + n4);
      Bs[(n4 + 0) * 72 + k] = f2bf(v.x);
      Bs[(n4 + 1) * 72 + k] = f2bf(v.y);
      Bs[(n4 + 2) * 72 + k] = f2bf(v.z);
      Bs[(n4 + 3) * 72 + k] = f2bf(v.w);
    }
    __syncthreads();
    bf16x8 a[4][2], b[4][2];
    #pragma unroll
    for (int rt = 0; rt < 4; rt++) {
      a[rt][0] = *(const bf16x8*)(&As[(wm + rt * 16 + l15) * 72 + quad * 8]);
      a[rt][1] = *(const bf16x8*)(&As[(wm + rt * 16 + l15) * 72 + 32 + quad * 8]);
    }
    #pragma unroll
    for (int ct = 0; ct < 4; ct++) {
      b[ct][0] = *(const bf16x8*)(&Bs[(wn + ct * 16 + l15) * 72 + quad * 8]);
      b[ct][1] = *(const bf16x8*)(&Bs[(wn + ct * 16 + l15) * 72 + 32 + quad * 8]);
    }
    #pragma unroll
    for (int rt = 0; rt < 4; rt++)
      #pragma unroll
      for (int ct = 0; ct < 4; ct++) {
        acc[rt][ct] = __builtin_amdgcn_mfma_f32_16x16x32_bf16(a[rt][0], b[ct][0], acc[rt][ct], 0, 0, 0);
        acc[rt][ct] = __builtin_amdgcn_mfma_f32_16x16x32_bf16(a[rt][1], b[ct][1], acc[rt][ct], 0, 0, 0);
      }
  }
  #pragma unroll
  for (int rt = 0; rt < 4; rt++) {
    const int row = r0 + wm + rt * 16 + quad * 4;
    #pragma unroll
    for (int ct = 0; ct < 4; ct++) {
      const int gc = n0 + wn + ct * 16 + l15;
      const float bc = wb[gc];
      #pragma unroll
      for (int r = 0; r < 4; r++)
        out[(size_t)(row + r) * 256 + gc] = acc[rt][ct][r] + bc;
    }
  }
}

// ---------- launch ----------
extern "C" void kernel_launch(void* const* d_in, const int* in_sizes, int n_in,
                              void* d_out, int out_size, void* d_ws, size_t ws_size,
                              hipStream_t stream) {
  (void)in_sizes; (void)n_in; (void)out_size; (void)ws_size;
  const float* x            = (const float*)d_in[0];
  const float* qkv_w        = (const float*)d_in[1];
  const float* qkv_b        = (const float*)d_in[2];
  const float* proj_w       = (const float*)d_in[3];
  const float* proj_b       = (const float*)d_in[4];
  const float* logit_scale  = (const float*)d_in[5];
  const float* val_res_sc   = (const float*)d_in[6];
  const float* mlp1_w       = (const float*)d_in[7];
  const float* mlp1_b       = (const float*)d_in[8];
  const float* mlp2_w       = (const float*)d_in[9];
  const float* bias_scale   = (const float*)d_in[10];
  float* out = (float*)d_out;

  // workspace carve (bf16 elements): q,k,v: [512,8,256,32] (v transposed [512,8,32,256]);
  // attn: [512,256,256]; bq/bk: [8,256,32].  Total ~256.3 MB.
  const size_t QKV_ELEMS = (size_t)512 * 8 * 256 * 32;   // 33,554,432
  unsigned short* q_ws    = (unsigned short*)d_ws;
  unsigned short* k_ws    = q_ws + QKV_ELEMS;
  unsigned short* v_ws    = k_ws + QKV_ELEMS;
  unsigned short* attn_ws = v_ws + QKV_ELEMS;
  unsigned short* bq_ws   = attn_ws + QKV_ELEMS;
  unsigned short* bk_ws   = bq_ws + 8 * 256 * 32;

  bias_kernel<<<dim3(8, 8), 256, 0, stream>>>(mlp1_w, mlp1_b, mlp2_w, bias_scale, bq_ws, bk_ws);
  qkv_kernel<<<dim3(6, 1024), 256, 0, stream>>>(x, qkv_w, qkv_b, logit_scale, q_ws, k_ws, v_ws);
  attn_kernel<<<dim3(4096), 256, 0, stream>>>(q_ws, k_ws, v_ws, bq_ws, bk_ws, val_res_sc, attn_ws);
  proj_kernel<<<dim3(2, 1024), 256, 0, stream>>>(attn_ws, proj_w, proj_b, out);
}

// Round 2
// 766.712 us; speedup vs baseline: 1.4988x; 1.4988x over previous
//
#include <hip/hip_runtime.h>

// ---------- types / helpers ----------
typedef __attribute__((ext_vector_type(8))) short bf16x8;   // MFMA A/B frag (4 VGPRs)
typedef __attribute__((ext_vector_type(4))) float f32x4;    // MFMA C/D frag
typedef __attribute__((ext_vector_type(4))) unsigned short us4_t;   // 8B bf16 store

__device__ __forceinline__ unsigned short f2bf(float f) {   // RNE fp32->bf16
  unsigned u = __builtin_bit_cast(unsigned, f);
  u += 0x7fffu + ((u >> 16) & 1u);
  return (unsigned short)(u >> 16);
}
__device__ __forceinline__ float bf2f(unsigned short h) {
  unsigned u = ((unsigned)h) << 16;
  return __builtin_bit_cast(float, u);
}
// async global->LDS DMA, 16B/lane. LDS dst is wave-uniform base + lane*16 (m97/m104).
__device__ __forceinline__ void async16(void* lds, const void* g) {
  __builtin_amdgcn_global_load_lds(
      (const __attribute__((address_space(1))) unsigned int*)g,
      (__attribute__((address_space(3))) unsigned int*)lds, 16, 0, 0);
}

// ---------- K_pre0: x fp32 -> bf16 (flat) ----------
__global__ __launch_bounds__(256) void xcvt_kernel(const float* __restrict__ x,
                                                   unsigned short* __restrict__ xb) {
  size_t base = ((size_t)blockIdx.x * 256 + threadIdx.x) * 16;
  #pragma unroll
  for (int i = 0; i < 4; i++) {
    float4 v = *(const float4*)(x + base + i * 4);
    us4_t p;
    p[0] = f2bf(v.x); p[1] = f2bf(v.y); p[2] = f2bf(v.z); p[3] = f2bf(v.w);
    *(us4_t*)(xb + base + i * 4) = p;
  }
}

// ---------- K_pre1: w [256][N] fp32 -> wT [N][256] bf16 (transpose+convert, once) ----------
__global__ __launch_bounds__(256) void wtcvt_kernel(const float* __restrict__ w,
                                                    unsigned short* __restrict__ wT, int N) {
  int flat = (blockIdx.x * 256 + threadIdx.x) * 4;   // over 256*N elems
  int k = flat / N, n = flat - k * N;                // 4 consecutive n, same k
  float4 v = *(const float4*)(w + flat);
  wT[(size_t)(n + 0) * 256 + k] = f2bf(v.x);
  wT[(size_t)(n + 1) * 256 + k] = f2bf(v.y);
  wT[(size_t)(n + 2) * 256 + k] = f2bf(v.z);
  wT[(size_t)(n + 3) * 256 + k] = f2bf(v.w);
}

// ---------- K0: rank-factored neural position bias -> bq/bk [H][256][32] bf16 ----------
__global__ __launch_bounds__(256) void bias_kernel(
    const float* __restrict__ mlp1_w, const float* __restrict__ mlp1_b,
    const float* __restrict__ mlp2_w, const float* __restrict__ bias_scale,
    unsigned short* __restrict__ bq_ws, unsigned short* __restrict__ bk_ws) {
  const int h = blockIdx.x;
  const int n = blockIdx.y * 32 + (threadIdx.x >> 3);
  const int rbase = (threadIdx.x & 7) * 4;
  const float inv_denom = 0.36067376022224085f;  // 1/log(16)
  const float c0 = log1pf((float)(n >> 4)) * inv_denom;
  const float c1 = log1pf((float)(n & 15)) * inv_denom;
  float hf[128];
  for (int j = 0; j < 128; j++) {
    float t = fmaf(c0, mlp1_w[j], fmaf(c1, mlp1_w[128 + j], mlp1_b[j]));
    hf[j] = 0.5f * t * (1.0f + erff(t * 0.70710678118654752f));  // exact gelu
  }
  const float bs = bias_scale[0];
  for (int i = 0; i < 4; i++) {
    int r = rbase + i;
    const float* wcol = mlp2_w + h * 64 + r;
    float sq = 0.f, sk = 0.f;
    for (int j = 0; j < 128; j++) {
      sq = fmaf(hf[j], wcol[j * 512], sq);
      sk = fmaf(hf[j], wcol[j * 512 + 32], sk);
    }
    bq_ws[(h * 256 + n) * 32 + r] = f2bf(bs / (1.f + expf(-sq)));
    bk_ws[(h * 256 + n) * 32 + r] = f2bf(1.f / (1.f + expf(-sk)));
  }
}

// ---------- K1: qkv GEMM (m97 structure). A=xb [M][256], B=wT [768][256], both bf16 k-contig.
// 128x128 tile, BK=64, 256 threads; DMA staging, unpadded stride-64 LDS.
__global__ __launch_bounds__(256) void qkv_kernel(
    const unsigned short* __restrict__ xb, const unsigned short* __restrict__ wT,
    const float* __restrict__ wb, const float* __restrict__ logit_scale,
    unsigned short* __restrict__ q_ws, unsigned short* __restrict__ k_ws,
    unsigned short* __restrict__ v_ws) {
  __shared__ unsigned short As[128 * 64];
  __shared__ unsigned short Bs[128 * 64];
  const int tid = threadIdx.x;
  const int n0 = blockIdx.x * 128, r0 = blockIdx.y * 128;
  const int lane = tid & 63, wv = tid >> 6, quad = lane >> 4, l15 = lane & 15;
  const int wm = (wv & 1) * 64, wn = (wv >> 1) * 64;

  f32x4 acc[4][4];
  #pragma unroll
  for (int i = 0; i < 4; i++)
    #pragma unroll
    for (int j = 0; j < 4; j++) acc[i][j] = (f32x4){0.f, 0.f, 0.f, 0.f};

  for (int kk = 0; kk < 256; kk += 64) {
    __syncthreads();
    #pragma unroll
    for (int i = 0; i < 4; i++) {            // flat = tid*8 + i*2048: lane-contig 16B
      int flat = tid * 8 + i * 2048;
      int row = flat >> 6, kc = flat & 63;
      async16(&As[flat], xb + (size_t)(r0 + row) * 256 + kk + kc);
      async16(&Bs[flat], wT + (size_t)(n0 + row) * 256 + kk + kc);
    }
    __syncthreads();                          // barrier drains vmcnt (m97)
    bf16x8 a[4][2], b[4][2];
    #pragma unroll
    for (int rt = 0; rt < 4; rt++) {
      a[rt][0] = *(const bf16x8*)(&As[(wm + rt * 16 + l15) * 64 + quad * 8]);
      a[rt][1] = *(const bf16x8*)(&As[(wm + rt * 16 + l15) * 64 + 32 + quad * 8]);
    }
    #pragma unroll
    for (int ct = 0; ct < 4; ct++) {
      b[ct][0] = *(const bf16x8*)(&Bs[(wn + ct * 16 + l15) * 64 + quad * 8]);
      b[ct][1] = *(const bf16x8*)(&Bs[(wn + ct * 16 + l15) * 64 + 32 + quad * 8]);
    }
    #pragma unroll
    for (int rt = 0; rt < 4; rt++)
      #pragma unroll
      for (int ct = 0; ct < 4; ct++) {
        acc[rt][ct] = __builtin_amdgcn_mfma_f32_16x16x32_bf16(a[rt][0], b[ct][0], acc[rt][ct], 0, 0, 0);
        acc[rt][ct] = __builtin_amdgcn_mfma_f32_16x16x32_bf16(a[rt][1], b[ct][1], acc[rt][ct], 0, 0, 0);
      }
  }
  // epilogue (verified R1): C/D layout col=lane&15, row=quad*4+reg
  #pragma unroll
  for (int rt = 0; rt < 4; rt++) {
    const int rowb = r0 + wm + rt * 16 + quad * 4;
    const int bb = rowb >> 8, n = rowb & 255;
    #pragma unroll
    for (int ct = 0; ct < 4; ct++) {
      const int gc = n0 + wn + ct * 16 + l15;
      const int s = gc >> 8, rem = gc & 255, h = rem >> 5, d = rem & 31;
      const float bc = wb[gc];
      if (s == 2) {  // v transposed [B,H,32,N]
        us4_t pk;
        #pragma unroll
        for (int r = 0; r < 4; r++) pk[r] = f2bf(acc[rt][ct][r] + bc);
        *(us4_t*)(v_ws + ((size_t)(bb * 8 + h) * 32 + d) * 256 + n) = pk;
      } else {
        const float sc = (s == 0) ? logit_scale[h] : 1.0f;
        unsigned short* dst = (s == 0) ? q_ws : k_ws;
        #pragma unroll
        for (int r = 0; r < 4; r++)
          dst[((size_t)(bb * 8 + h) * 256 + (n + r)) * 32 + d] = f2bf((acc[rt][ct][r] + bc) * sc);
      }
    }
  }
}

// ---------- K2: attention per (b,h). LDS = exactly 80 KB -> 2 blocks/CU.
__global__ __launch_bounds__(256) void attn_kernel(
    const unsigned short* __restrict__ q_ws, const unsigned short* __restrict__ k_ws,
    const unsigned short* __restrict__ v_ws, const unsigned short* __restrict__ bq_ws,
    const unsigned short* __restrict__ bk_ws, const float* __restrict__ val_res_scale,
    unsigned short* __restrict__ attn_ws) {
  __shared__ unsigned short kk_s[256 * 32];   // [key][d]     16 KB
  __shared__ unsigned short bk_s[256 * 32];   // [key][r]     16 KB
  __shared__ unsigned short vT[32 * 256];     // [d][key]     16 KB
  __shared__ unsigned short Pb[4][16 * 256];  // per-wave P, XOR-swizzled chunks  32 KB

  const int tid = threadIdx.x;
  const int bh = blockIdx.x, b = bh >> 3, h = bh & 7;
  const size_t base = (size_t)bh * (256 * 32);
  const int lane = tid & 63, wv = tid >> 6, quad = lane >> 4, l15 = lane & 15;

  // staging: three contiguous 16 KB slices via DMA (4 instr/thread each)
  #pragma unroll
  for (int i = 0; i < 4; i++) {
    int flat = tid * 8 + i * 2048;
    async16(&kk_s[flat], k_ws + base + flat);
    async16(&bk_s[flat], bk_ws + (size_t)h * 8192 + flat);
    async16(&vT[flat], v_ws + base + flat);
  }
  __syncthreads();

  // v_mean -> registers (scratch reduction aliased into Pb, consumed before P writes)
  float* red = (float*)&Pb[0][0];
  {
    int d = tid & 31, seg = tid >> 5;
    float s = 0.f;
    for (int i = 0; i < 32; i++) s += bf2f(vT[d * 256 + seg * 32 + i]);
    red[seg * 32 + d] = s;
  }
  __syncthreads();
  if (tid < 32) {
    float s = 0.f;
    for (int seg = 0; seg < 8; seg++) s += red[seg * 32 + tid];
    red[256 + tid] = val_res_scale[h] * s * (1.0f / 256.0f);
  }
  __syncthreads();
  const float vm_lo = red[256 + l15];
  const float vm_hi = red[256 + 16 + l15];
  __syncthreads();   // all reads of red done before Pb is overwritten

  unsigned short* P = Pb[wv];
  for (int rt = 0; rt < 4; rt++) {
    const int m = wv * 64 + rt * 16 + l15;
    bf16x8 aq = *(const bf16x8*)(q_ws + base + (size_t)m * 32 + quad * 8);
    bf16x8 abq = *(const bf16x8*)(bq_ws + (size_t)h * 8192 + (size_t)m * 32 + quad * 8);
    f32x4 sacc[16];
    #pragma unroll
    for (int ct = 0; ct < 16; ct++) {
      bf16x8 b0 = *(const bf16x8*)(&kk_s[(ct * 16 + l15) * 32 + quad * 8]);
      bf16x8 b1 = *(const bf16x8*)(&bk_s[(ct * 16 + l15) * 32 + quad * 8]);
      f32x4 c = {0.f, 0.f, 0.f, 0.f};
      c = __builtin_amdgcn_mfma_f32_16x16x32_bf16(aq, b0, c, 0, 0, 0);
      c = __builtin_amdgcn_mfma_f32_16x16x32_bf16(abq, b1, c, 0, 0, 0);
      sacc[ct] = c;
    }
    float rsum[4];
    #pragma unroll
    for (int r = 0; r < 4; r++) {
      float mx = sacc[0][r];
      #pragma unroll
      for (int ct = 1; ct < 16; ct++) mx = fmaxf(mx, sacc[ct][r]);
      #pragma unroll
      for (int off = 1; off < 16; off <<= 1) mx = fmaxf(mx, __shfl_xor(mx, off, 16));
      float s = 0.f;
      #pragma unroll
      for (int ct = 0; ct < 16; ct++) {
        float e = __expf(sacc[ct][r] - mx);
        sacc[ct][r] = e;
        s += e;
      }
      #pragma unroll
      for (int off = 1; off < 16; off <<= 1) s += __shfl_xor(s, off, 16);
      rsum[r] = s;
    }
    // P write: row=quad*4+r, col=ct*16+l15; chunk c' = (col>>3) ^ (row&7)
    #pragma unroll
    for (int ct = 0; ct < 16; ct++)
      #pragma unroll
      for (int r = 0; r < 4; r++) {
        int row = quad * 4 + r;
        int cs = (ct * 2 + (l15 >> 3)) ^ (row & 7);
        P[row * 256 + cs * 8 + (l15 & 7)] = f2bf(sacc[ct][r]);
      }
    __threadfence_block();
    f32x4 o0 = {0.f, 0.f, 0.f, 0.f}, o1 = {0.f, 0.f, 0.f, 0.f};
    #pragma unroll
    for (int s = 0; s < 8; s++) {   // A-frag row=l15, k chunk (s*4+quad) ^ (l15&7)
      int cs = (s * 4 + quad) ^ (l15 & 7);
      bf16x8 ap = *(const bf16x8*)(&P[l15 * 256 + cs * 8]);
      bf16x8 bv0 = *(const bf16x8*)(&vT[l15 * 256 + s * 32 + quad * 8]);
      bf16x8 bv1 = *(const bf16x8*)(&vT[(16 + l15) * 256 + s * 32 + quad * 8]);
      o0 = __builtin_amdgcn_mfma_f32_16x16x32_bf16(ap, bv0, o0, 0, 0, 0);
      o1 = __builtin_amdgcn_mfma_f32_16x16x32_bf16(ap, bv1, o1, 0, 0, 0);
    }
    const int nrow = wv * 64 + rt * 16 + quad * 4;
    const size_t obase = ((size_t)b * 256 + nrow) * 256 + h * 32;
    #pragma unroll
    for (int r = 0; r < 4; r++) {
      float inv = 1.0f / rsum[r];
      attn_ws[obase + (size_t)r * 256 + l15] = f2bf(o0[r] * inv + vm_lo);
      attn_ws[obase + (size_t)r * 256 + 16 + l15] = f2bf(o1[r] * inv + vm_hi);
    }
    __threadfence_block();  // P reads drained before next rt overwrites
  }
}

// ---------- K3: out = attn @ proj_w + proj_b (m97 structure, fp32 out) ----------
__global__ __launch_bounds__(256) void proj_kernel(
    const unsigned short* __restrict__ A, const unsigned short* __restrict__ wT,
    const float* __restrict__ wb, float* __restrict__ out) {
  __shared__ unsigned short As[128 * 64];
  __shared__ unsigned short Bs[128 * 64];
  const int tid = threadIdx.x;
  const int n0 = blockIdx.x * 128, r0 = blockIdx.y * 128;
  const int lane = tid & 63, wv = tid >> 6, quad = lane >> 4, l15 = lane & 15;
  const int wm = (wv & 1) * 64, wn = (wv >> 1) * 64;

  f32x4 acc[4][4];
  #pragma unroll
  for (int i = 0; i < 4; i++)
    #pragma unroll
    for (int j = 0; j < 4; j++) acc[i][j] = (f32x4){0.f, 0.f, 0.f, 0.f};

  for (int kk = 0; kk < 256; kk += 64) {
    __syncthreads();
    #pragma unroll
    for (int i = 0; i < 4; i++) {
      int flat = tid * 8 + i * 2048;
      int row = flat >> 6, kc = flat & 63;
      async16(&As[flat], A + (size_t)(r0 + row) * 256 + kk + kc);
      async16(&Bs[flat], wT + (size_t)(n0 + row) * 256 + kk + kc);
    }
    __syncthreads();
    bf16x8 a[4][2], b[4][2];
    #pragma unroll
    for (int rt = 0; rt < 4; rt++) {
      a[rt][0] = *(const bf16x8*)(&As[(wm + rt * 16 + l15) * 64 + quad * 8]);
      a[rt][1] = *(const bf16x8*)(&As[(wm + rt * 16 + l15) * 64 + 32 + quad * 8]);
    }
    #pragma unroll
    for (int ct = 0; ct < 4; ct++) {
      b[ct][0] = *(const bf16x8*)(&Bs[(wn + ct * 16 + l15) * 64 + quad * 8]);
      b[ct][1] = *(const bf16x8*)(&Bs[(wn + ct * 16 + l15) * 64 + 32 + quad * 8]);
    }
    #pragma unroll
    for (int rt = 0; rt < 4; rt++)
      #pragma unroll
      for (int ct = 0; ct < 4; ct++) {
        acc[rt][ct] = __builtin_amdgcn_mfma_f32_16x16x32_bf16(a[rt][0], b[ct][0], acc[rt][ct], 0, 0, 0);
        acc[rt][ct] = __builtin_amdgcn_mfma_f32_16x16x32_bf16(a[rt][1], b[ct][1], acc[rt][ct], 0, 0, 0);
      }
  }
  #pragma unroll
  for (int rt = 0; rt < 4; rt++) {
    const int row = r0 + wm + rt * 16 + quad * 4;
    #pragma unroll
    for (int ct = 0; ct < 4; ct++) {
      const int gc = n0 + wn + ct * 16 + l15;
      const float bc = wb[gc];
      #pragma unroll
      for (int r = 0; r < 4; r++)
        out[(size_t)(row + r) * 256 + gc] = acc[rt][ct][r] + bc;
    }
  }
}

// ---------- launch ----------
extern "C" void kernel_launch(void* const* d_in, const int* in_sizes, int n_in,
                              void* d_out, int out_size, void* d_ws, size_t ws_size,
                              hipStream_t stream) {
  (void)in_sizes; (void)n_in; (void)out_size; (void)ws_size;
  const float* x           = (const float*)d_in[0];
  const float* qkv_w       = (const float*)d_in[1];
  const float* qkv_b       = (const float*)d_in[2];
  const float* proj_w      = (const float*)d_in[3];
  const float* proj_b      = (const float*)d_in[4];
  const float* logit_scale = (const float*)d_in[5];
  const float* val_res_sc  = (const float*)d_in[6];
  const float* mlp1_w      = (const float*)d_in[7];
  const float* mlp1_b      = (const float*)d_in[8];
  const float* mlp2_w      = (const float*)d_in[9];
  const float* bias_scale  = (const float*)d_in[10];
  float* out = (float*)d_out;

  // ws carve (bf16 elems). xb aliases attn_ws: xb consumed by qkv before attn writes it.
  const size_t QKV_ELEMS = (size_t)512 * 8 * 256 * 32;   // 33,554,432 (67 MB)
  unsigned short* q_ws    = (unsigned short*)d_ws;
  unsigned short* k_ws    = q_ws + QKV_ELEMS;
  unsigned short* v_ws    = k_ws + QKV_ELEMS;
  unsigned short* attn_ws = v_ws + QKV_ELEMS;            // also xb
  unsigned short* xb      = attn_ws;
  unsigned short* bq_ws   = attn_ws + QKV_ELEMS;
  unsigned short* bk_ws   = bq_ws + 8 * 256 * 32;
  unsigned short* wT      = bk_ws + 8 * 256 * 32;        // [768][256]
  unsigned short* pwT     = wT + 768 * 256;              // [256][256]

  xcvt_kernel<<<dim3(8192), 256, 0, stream>>>(x, xb);
  wtcvt_kernel<<<dim3(192), 256, 0, stream>>>(qkv_w, wT, 768);
  wtcvt_kernel<<<dim3(64), 256, 0, stream>>>(proj_w, pwT, 256);
  bias_kernel<<<dim3(8, 8), 256, 0, stream>>>(mlp1_w, mlp1_b, mlp2_w, bias_scale, bq_ws, bk_ws);
  qkv_kernel<<<dim3(6, 1024), 256, 0, stream>>>(xb, wT, qkv_b, logit_scale, q_ws, k_ws, v_ws);
  attn_kernel<<<dim3(4096), 256, 0, stream>>>(q_ws, k_ws, v_ws, bq_ws, bk_ws, val_res_sc, attn_ws);
  proj_kernel<<<dim3(2, 1024), 256, 0, stream>>>(attn_ws, pwT, proj_b, out);
}